// Round 10
// baseline (135.440 us; speedup 1.0000x reference)
//
#include <hip/hip_runtime.h>
#include <hip/hip_bf16.h>

#define S0 480
#define S1 360
#define S2 32
#define SLAB (S1 * S2)                 // 11520
#define CH 32
#define EPS 1e-5f
#define SLOPE 0.01f

#define NCOL (2 * S0 * S1)             // 345600 columns (b,c0,c1)
#define SCAN_BLKS (NCOL / 256)         // 1350

typedef short short8 __attribute__((ext_vector_type(8)));
typedef float f32x16 __attribute__((ext_vector_type(16)));

__device__ __forceinline__ unsigned short f2b(float f) {
    union { __hip_bfloat16 b; unsigned short u; } v;
    v.b = __float2bfloat16(f);
    return v.u;
}

// ---- clear mask + stats (rocclr fillBuffer is slow for small fills) -----
__global__ __launch_bounds__(256) void clear_k(uint4* __restrict__ mask,
                                               float* __restrict__ stats)
{
    int i = blockIdx.x * 256 + threadIdx.x;
    if (i < NCOL / 4) mask[i] = make_uint4(0u, 0u, 0u, 0u);
    if (i < 64) stats[i] = 0.f;
}

// ---- scatter: set presence bit (atomicOr = order-independent) -----------
__global__ __launch_bounds__(256) void scatter_or_k(
    const int4* __restrict__ coords, unsigned int* __restrict__ mask, int n)
{
    int i = blockIdx.x * 256 + threadIdx.x;
    if (i < n) {
        int4 c = coords[i];
        int col = (c.x * S0 + c.y) * S1 + c.z;
        atomicOr(&mask[col], 1u << c.w);
    }
}

// ---- scanA: per-256-col block popcount sums; block 0 also packs weights -
__global__ __launch_bounds__(256) void scanA_k(
    const unsigned int* __restrict__ mask, int* __restrict__ bsum,
    const float* __restrict__ weight, short8* __restrict__ bfrag)
{
    int t = threadIdx.x;
    int pc = __popc(mask[blockIdx.x * 256 + t]);
#pragma unroll
    for (int m = 32; m > 0; m >>= 1) pc += __shfl_xor(pc, m, 64);
    __shared__ int red[4];
    if ((t & 63) == 0) red[t >> 6] = pc;
    __syncthreads();
    if (t == 0) bsum[blockIdx.x] = red[0] + red[1] + red[2] + red[3];

    if (blockIdx.x == 0 && t < 64) {
        int half = t >> 5;
        int col  = t & 31;
#pragma unroll
        for (int k = 0; k < 9; ++k)
#pragma unroll
            for (int h = 0; h < 2; ++h) {
                short8 fr;
#pragma unroll
                for (int j = 0; j < 8; ++j) {
                    int ic = h * 16 + half * 8 + j;
                    fr[j] = (short)f2b(weight[k * (CH * CH) + ic * CH + col]);
                }
                bfrag[(k * 2 + h) * 64 + t] = fr;
            }
    }
}

// ---- scanBC: tab[col] = {mask, global exclusive rank base} --------------
__global__ __launch_bounds__(256) void scanBC_k(
    const unsigned int* __restrict__ mask, const int* __restrict__ bsum,
    uint2* __restrict__ tab)
{
    int t = threadIdx.x;
    int b = blockIdx.x;

    int partial = 0;
    for (int j = t; j < b; j += 256) partial += bsum[j];
#pragma unroll
    for (int m = 32; m > 0; m >>= 1) partial += __shfl_xor(partial, m, 64);
    __shared__ int red[4];
    if ((t & 63) == 0) red[t >> 6] = partial;
    __syncthreads();
    int base = red[0] + red[1] + red[2] + red[3];

    int col = b * 256 + t;
    unsigned int m = mask[col];
    int pc = __popc(m);
    __shared__ int sa[256], sb[256];
    sa[t] = pc; __syncthreads();
    int* src = sa; int* dst = sb;
#pragma unroll
    for (int off = 1; off < 256; off <<= 1) {
        dst[t] = src[t] + (t >= off ? src[t - off] : 0);
        __syncthreads();
        int* tmp = src; src = dst; dst = tmp;
    }
    int excl = src[t] - pc + base;
    tab[col] = make_uint2(m, (unsigned int)excl);
}

// ---- rank: pinfo[rank]={i,lin} (scatter into L2) + rankof[i] (coalesced) -
__global__ __launch_bounds__(256) void rank_k(
    const int4*  __restrict__ coords,
    const uint2* __restrict__ tab,
    uint2*       __restrict__ pinfo,
    int*         __restrict__ rankof,
    int n)
{
    int i = blockIdx.x * 256 + threadIdx.x;
    if (i >= n) return;
    int4 c = coords[i];
    int col = (c.x * S0 + c.y) * S1 + c.z;
    int lin = col * 32 + c.w;
    uint2 tv = tab[col];
    int rank = (int)tv.y + __popc(tv.x & ((1u << c.w) - 1u));
    pinfo[rank] = make_uint2((unsigned int)i, (unsigned int)lin);
    rankof[i] = rank;
}

// ---- pack: XCD-chunked rank ranges (same partition as conv) -------------
__global__ __launch_bounds__(256) void pack_k(
    const float* __restrict__ features,
    const uint2* __restrict__ pinfo,
    unsigned short* __restrict__ featb,  // [rank][32] bf16
    int n, int ntile)
{
    int NB  = gridDim.x;
    int bpx = NB >> 3;                    // blocks per XCD
    int xcd = blockIdx.x & 7;
    int ibx = blockIdx.x >> 3;
    int chunk = (ntile + 7) >> 3;
    int rstart = xcd * chunk * 32;
    int rend   = min((xcd + 1) * chunk, ntile) * 32;
    if (rend > n) rend = n;

    int t = threadIdx.x;
    int j = t & 7;                        // 8 lanes x 16B = one 128B row
    int sub = t >> 3;                     // 32 rows per iteration
    for (int row = rstart + ibx * 32 + sub; row < rend; row += bpx * 32) {
        unsigned int orig = pinfo[row].x;
        float4 f = ((const float4*)(features + (size_t)orig * CH))[j];
        ushort4 u;
        u.x = f2b(f.x); u.y = f2b(f.y); u.z = f2b(f.z); u.w = f2b(f.w);
        ((ushort4*)(featb + (size_t)row * CH))[j] = u;
    }
}

// ---- conv: __launch_bounds__(256,2) so all 18 gathers stay in flight ----
__global__ __launch_bounds__(256, 2) void conv_sorted_k(
    const unsigned short* __restrict__ featb,
    const uint2* __restrict__ pinfo,
    const uint2* __restrict__ tab,
    const short8* __restrict__ bfrag,
    unsigned short* __restrict__ xout,   // bf16 x, rank order [n][32]
    float*        __restrict__ stats,    // [64] f32, atomically accumulated
    int n, int ntile)
{
    int tid  = threadIdx.x;
    int lane = tid & 63;
    int wv   = tid >> 6;
    int half = lane >> 5;
    int col  = lane & 31;

    short8 B[9][2];
#pragma unroll
    for (int t = 0; t < 9; ++t) {
        B[t][0] = bfrag[(t * 2 + 0) * 64 + lane];
        B[t][1] = bfrag[(t * 2 + 1) * 64 + lane];
    }

    // partition: XCD chunk -> per-wave contiguous run of tiles
    int NB  = gridDim.x;
    int bpx = NB >> 3;
    int xcd = blockIdx.x & 7;
    int ibx = blockIdx.x >> 3;
    int chunk = (ntile + 7) >> 3;
    int wpx = bpx * 4;
    int run = (chunk + wpx - 1) / wpx;
    int wix = ibx * 4 + wv;
    int xend = min((xcd + 1) * chunk, ntile);
    int t0 = xcd * chunk + wix * run;
    int t1 = min(t0 + run, xend);

    float s = 0.f, qq = 0.f;

    for (int tile = t0; tile < t1; ++tile) {
        int p = tile * 32 + col;
        bool live = (p < n);
        int pc = live ? p : 0;

        uint2 pi = pinfo[pc];
        int lin = (int)pi.y;
        int c2 = lin & 31;
        int colv = lin >> 5;
        int c0 = (lin / SLAB) % S0;

        int nbr[9];
#pragma unroll
        for (int d0 = 0; d0 < 3; ++d0) {
            int n0 = c0 + d0 - 1;
            bool v0 = (n0 >= 0) & (n0 < S0) & live;
            uint2 tv = v0 ? tab[colv + (d0 - 1) * S1] : make_uint2(0u, 0u);
#pragma unroll
            for (int d2 = 0; d2 < 3; ++d2) {
                int n2 = c2 + d2 - 1;
                int rk = -1;
                if (v0 && n2 >= 0 && n2 < S2 && ((tv.x >> n2) & 1u))
                    rk = (int)tv.y + __popc(tv.x & ((1u << n2) - 1u));
                nbr[d0 * 3 + d2] = rk;
            }
        }

        bool act[9];
#pragma unroll
        for (int t = 0; t < 9; ++t) act[t] = (__any(nbr[t] >= 0) != 0);

        // stage ALL 18 gathers (with 2-wave launch bounds the allocator
        // can keep them live -> one vmcnt wait instead of nine)
        short8 A0[9], A1[9];
#pragma unroll
        for (int t = 0; t < 9; ++t) {
            short8 z;
#pragma unroll
            for (int j = 0; j < 8; ++j) z[j] = 0;
            A0[t] = z; A1[t] = z;
            int nb = nbr[t];
            if (nb >= 0) {
                const short* fp = (const short*)featb + (size_t)nb * CH;
                A0[t] = *(const short8*)(fp + half * 8);
                A1[t] = *(const short8*)(fp + 16 + half * 8);
            }
        }

        f32x16 acc;
#pragma unroll
        for (int i = 0; i < 16; ++i) acc[i] = 0.f;
#pragma unroll
        for (int t = 0; t < 9; ++t) {
            if (act[t]) {
                acc = __builtin_amdgcn_mfma_f32_32x32x16_bf16(A0[t], B[t][0], acc, 0, 0, 0);
                acc = __builtin_amdgcn_mfma_f32_32x32x16_bf16(A1[t], B[t][1], acc, 0, 0, 0);
            }
        }

        // C/D layout: col = lane&31, row = (i&3) + 8*(i>>2) + 4*half
#pragma unroll
        for (int i = 0; i < 16; ++i) {
            float v = acc[i];
            v = v >= 0.f ? v : SLOPE * v;
            int row = (i & 3) + 8 * (i >> 2) + 4 * half;
            int prow = tile * 32 + row;
            if (prow < n) {
                xout[(size_t)prow * CH + col] = f2b(v);
                s += v; qq += v * v;
            }
        }
    }

    s  += __shfl_xor(s, 32);
    qq += __shfl_xor(qq, 32);

    __shared__ float lsum[4][32];
    __shared__ float lsq[4][32];
    if (lane < 32) { lsum[wv][col] = s; lsq[wv][col] = qq; }
    __syncthreads();
    if (tid < 32) {
        atomicAdd(&stats[tid],
                  lsum[0][tid] + lsum[1][tid] + lsum[2][tid] + lsum[3][tid]);
    } else if (tid < 64) {
        int cc = tid - 32;
        atomicAdd(&stats[CH + cc],
                  lsq[0][cc] + lsq[1][cc] + lsq[2][cc] + lsq[3][cc]);
    }
}

// ---- BN normalize: gather xb by rank, fully-coalesced fp32 out write ----
__global__ __launch_bounds__(256) void bn_gather_k(
    const unsigned short* __restrict__ xb,
    const int*   __restrict__ rankof,
    const float* __restrict__ stats,
    const float* __restrict__ gamma,
    const float* __restrict__ beta,
    float* __restrict__ out,
    int n)
{
    int total = n * 4;                        // (orig row, 8-ch slot) pairs
    int stride = gridDim.x * blockDim.x;      // multiple of 4
    int g = blockIdx.x * blockDim.x + threadIdx.x;
    int c8 = g & 3;

    float scale[8], shift[8];
    float rn = 1.0f / (float)n;
#pragma unroll
    for (int j = 0; j < 8; ++j) {
        int oc = c8 * 8 + j;
        float m  = stats[oc] * rn;
        float vv = stats[CH + oc] * rn - m * m;
        float iv = rsqrtf(vv + EPS) * gamma[oc];
        scale[j] = iv;
        shift[j] = beta[oc] - m * iv;
    }

    const short8* x8 = (const short8*)xb;
    for (; g < total; g += stride) {
        int i = g >> 2;                       // original row
        int rank = rankof[i];
        short8 v = x8[(size_t)rank * 4 + c8];
        float f[8];
#pragma unroll
        for (int j = 0; j < 8; ++j) {
            union { unsigned int u; float f; } w;
            w.u = ((unsigned int)(unsigned short)v[j]) << 16;
            f[j] = fmaf(w.f, scale[j], shift[j]);
        }
        float4* o = (float4*)(out + (size_t)i * CH + c8 * 8);  // coalesced
        o[0] = make_float4(f[0], f[1], f[2], f[3]);
        o[1] = make_float4(f[4], f[5], f[6], f[7]);
    }
}

extern "C" void kernel_launch(void* const* d_in, const int* in_sizes, int n_in,
                              void* d_out, int out_size, void* d_ws, size_t ws_size,
                              hipStream_t stream)
{
    const float* features = (const float*)d_in[0];
    const int4*  coords   = (const int4*)d_in[1];
    const float* weight   = (const float*)d_in[2];
    const float* gamma    = (const float*)d_in[3];
    const float* beta     = (const float*)d_in[4];
    float* out = (float*)d_out;

    int n = in_sizes[0] / CH;            // 400000
    int ntile = (n + 31) / 32;           // 12500
    int conv_blocks = 2048;

    // ws layout (256 B aligned sections)
    char* w = (char*)d_ws;
    unsigned int* mask = (unsigned int*)w;  w += (size_t)NCOL * 4;            // 1.38 MB
    float* stats = (float*)w;               w += 256;                         // 64 f32
    uint2* tab = (uint2*)w;                 w += (size_t)NCOL * 8;            // 2.76 MB
    int* bsum = (int*)w;                    w += ((size_t)SCAN_BLKS * 4 + 255) & ~(size_t)255;
    uint2* pinfo = (uint2*)w;               w += (size_t)n * 8;               // 3.2 MB
    int* rankof = (int*)w;                  w += (size_t)n * 4;               // 1.6 MB
    unsigned short* featb = (unsigned short*)w; w += (size_t)n * CH * 2;      // 25.6 MB
    unsigned short* xout = (unsigned short*)w;  w += (size_t)n * CH * 2;      // 25.6 MB
    short8* bfrag = (short8*)w;             w += 9 * 2 * 64 * sizeof(short8);

    clear_k<<<(NCOL / 4 + 255) / 256, 256, 0, stream>>>((uint4*)mask, stats);
    scatter_or_k<<<(n + 255) / 256, 256, 0, stream>>>(coords, mask, n);
    scanA_k<<<SCAN_BLKS, 256, 0, stream>>>(mask, bsum, weight, bfrag);
    scanBC_k<<<SCAN_BLKS, 256, 0, stream>>>(mask, bsum, tab);
    rank_k<<<(n + 255) / 256, 256, 0, stream>>>(coords, tab, pinfo, rankof, n);
    pack_k<<<2048, 256, 0, stream>>>(features, pinfo, featb, n, ntile);

    conv_sorted_k<<<conv_blocks, 256, 0, stream>>>(
        featb, pinfo, tab, bfrag, xout, stats, n, ntile);

    bn_gather_k<<<2048, 256, 0, stream>>>(xout, rankof, stats, gamma, beta, out, n);
}

// Round 11
// 104.299 us; speedup vs baseline: 1.2986x; 1.2986x over previous
//
#include <hip/hip_runtime.h>
#include <hip/hip_bf16.h>

#define S0 480
#define S1 360
#define S2 32
#define SLAB (S1 * S2)                 // 11520
#define CH 32
#define EPS 1e-5f
#define SLOPE 0.01f

#define NCOL (2 * S0 * S1)             // 345600 columns (b,c0,c1)
#define SCAN_BLKS (NCOL / 256)         // 1350

typedef short short8 __attribute__((ext_vector_type(8)));
typedef float f32x16 __attribute__((ext_vector_type(16)));

__device__ __forceinline__ unsigned short f2b(float f) {
    union { __hip_bfloat16 b; unsigned short u; } v;
    v.b = __float2bfloat16(f);
    return v.u;
}

// ---- clear mask + featb zero-row (rocclr fillBuffer is slow) ------------
__global__ __launch_bounds__(256) void clear_k(uint4* __restrict__ mask,
                                               uint4* __restrict__ zrow)
{
    int i = blockIdx.x * 256 + threadIdx.x;
    if (i < NCOL / 4) mask[i] = make_uint4(0u, 0u, 0u, 0u);
    if (blockIdx.x == 0 && threadIdx.x < 4)
        zrow[threadIdx.x] = make_uint4(0u, 0u, 0u, 0u);
}

// ---- scatter: set presence bit (atomicOr = order-independent) -----------
__global__ __launch_bounds__(256) void scatter_or_k(
    const int4* __restrict__ coords, unsigned int* __restrict__ mask, int n)
{
    int i = blockIdx.x * 256 + threadIdx.x;
    if (i < n) {
        int4 c = coords[i];
        int col = (c.x * S0 + c.y) * S1 + c.z;
        atomicOr(&mask[col], 1u << c.w);
    }
}

// ---- scanA: per-256-col block popcount sums; block 0 also packs weights -
__global__ __launch_bounds__(256) void scanA_k(
    const unsigned int* __restrict__ mask, int* __restrict__ bsum,
    const float* __restrict__ weight, short8* __restrict__ bfrag)
{
    int t = threadIdx.x;
    int pc = __popc(mask[blockIdx.x * 256 + t]);
#pragma unroll
    for (int m = 32; m > 0; m >>= 1) pc += __shfl_xor(pc, m, 64);
    __shared__ int red[4];
    if ((t & 63) == 0) red[t >> 6] = pc;
    __syncthreads();
    if (t == 0) bsum[blockIdx.x] = red[0] + red[1] + red[2] + red[3];

    if (blockIdx.x == 0 && t < 64) {
        int half = t >> 5;
        int col  = t & 31;
#pragma unroll
        for (int k = 0; k < 9; ++k)
#pragma unroll
            for (int h = 0; h < 2; ++h) {
                short8 fr;
#pragma unroll
                for (int j = 0; j < 8; ++j) {
                    int ic = h * 16 + half * 8 + j;
                    fr[j] = (short)f2b(weight[k * (CH * CH) + ic * CH + col]);
                }
                bfrag[(k * 2 + h) * 64 + t] = fr;
            }
    }
}

// ---- scanBC: tab[col] = {mask, global exclusive rank base} --------------
__global__ __launch_bounds__(256) void scanBC_k(
    const unsigned int* __restrict__ mask, const int* __restrict__ bsum,
    uint2* __restrict__ tab)
{
    int t = threadIdx.x;
    int b = blockIdx.x;

    int partial = 0;
    for (int j = t; j < b; j += 256) partial += bsum[j];
#pragma unroll
    for (int m = 32; m > 0; m >>= 1) partial += __shfl_xor(partial, m, 64);
    __shared__ int red[4];
    if ((t & 63) == 0) red[t >> 6] = partial;
    __syncthreads();
    int base = red[0] + red[1] + red[2] + red[3];

    int col = b * 256 + t;
    unsigned int m = mask[col];
    int pc = __popc(m);
    __shared__ int sa[256], sb[256];
    sa[t] = pc; __syncthreads();
    int* src = sa; int* dst = sb;
#pragma unroll
    for (int off = 1; off < 256; off <<= 1) {
        dst[t] = src[t] + (t >= off ? src[t - off] : 0);
        __syncthreads();
        int* tmp = src; src = dst; dst = tmp;
    }
    int excl = src[t] - pc + base;
    tab[col] = make_uint2(m, (unsigned int)excl);
}

// ---- rank: pinfo[rank]={i,lin} (scatter into L2) + rankof[i] (coalesced) -
__global__ __launch_bounds__(256) void rank_k(
    const int4*  __restrict__ coords,
    const uint2* __restrict__ tab,
    uint2*       __restrict__ pinfo,
    int*         __restrict__ rankof,
    int n)
{
    int i = blockIdx.x * 256 + threadIdx.x;
    if (i >= n) return;
    int4 c = coords[i];
    int col = (c.x * S0 + c.y) * S1 + c.z;
    int lin = col * 32 + c.w;
    uint2 tv = tab[col];
    int rank = (int)tv.y + __popc(tv.x & ((1u << c.w) - 1u));
    pinfo[rank] = make_uint2((unsigned int)i, (unsigned int)lin);
    rankof[i] = rank;
}

// ---- pack: XCD-chunked rank ranges (same partition as conv) -------------
__global__ __launch_bounds__(256) void pack_k(
    const float* __restrict__ features,
    const uint2* __restrict__ pinfo,
    unsigned short* __restrict__ featb,  // [rank][32] bf16
    int n, int ntile)
{
    int NB  = gridDim.x;
    int bpx = NB >> 3;                    // blocks per XCD
    int xcd = blockIdx.x & 7;
    int ibx = blockIdx.x >> 3;
    int chunk = (ntile + 7) >> 3;
    int rstart = xcd * chunk * 32;
    int rend   = min((xcd + 1) * chunk, ntile) * 32;
    if (rend > n) rend = n;

    int t = threadIdx.x;
    int j = t & 7;                        // 8 lanes x 16B = one 128B row
    int sub = t >> 3;                     // 32 rows per iteration
    for (int row = rstart + ibx * 32 + sub; row < rend; row += bpx * 32) {
        unsigned int orig = pinfo[row].x;
        float4 f = ((const float4*)(features + (size_t)orig * CH))[j];
        ushort4 u;
        u.x = f2b(f.x); u.y = f2b(f.y); u.z = f2b(f.z); u.w = f2b(f.w);
        ((ushort4*)(featb + (size_t)row * CH))[j] = u;
    }
}

// ---- conv: branch-free gathers (zero-row trick), XCD-chunked tiles ------
__global__ __launch_bounds__(256, 2) void conv_sorted_k(
    const unsigned short* __restrict__ featb,   // [n+1 rows][32], row n = zeros
    const uint2* __restrict__ pinfo,
    const uint2* __restrict__ tab,
    const short8* __restrict__ bfrag,
    unsigned short* __restrict__ xout,   // bf16 x, rank order [n][32]
    float*        __restrict__ stats_part, // [gridDim.x][64]
    int n, int ntile)
{
    int tid  = threadIdx.x;
    int lane = tid & 63;
    int wv   = tid >> 6;
    int half = lane >> 5;
    int col  = lane & 31;

    short8 B[9][2];
#pragma unroll
    for (int t = 0; t < 9; ++t) {
        B[t][0] = bfrag[(t * 2 + 0) * 64 + lane];
        B[t][1] = bfrag[(t * 2 + 1) * 64 + lane];
    }

    // XCD-chunked: consecutive tiles -> same XCD (bid&7 hw round-robin)
    int xcd = blockIdx.x & 7;
    int ibx = blockIdx.x >> 3;
    int chunk = (ntile + 7) >> 3;          // 1563
    int idx = ibx * 4 + wv;                // tile index within chunk
    int tile = xcd * chunk + idx;
    bool tlive = (idx < chunk) && (tile < ntile);

    float s = 0.f, qq = 0.f;

    if (tlive) {
        int p = tile * 32 + col;
        bool live = (p < n);
        int pc = live ? p : 0;

        uint2 pi = pinfo[pc];
        int lin = (int)pi.y;
        int c2 = lin & 31;
        int colv = lin >> 5;
        int c0 = (lin / SLAB) % S0;

        // phase 1: 3 unconditional tab loads (clamped index), branch-free
        int nbr[9];
#pragma unroll
        for (int d0 = 0; d0 < 3; ++d0) {
            int n0 = c0 + d0 - 1;
            bool v0 = (n0 >= 0) & (n0 < S0) & live;
            int cidx = colv + (d0 - 1) * S1;
            cidx = min(max(cidx, 0), NCOL - 1);
            uint2 tv = tab[cidx];
#pragma unroll
            for (int d2 = 0; d2 < 3; ++d2) {
                int n2 = c2 + d2 - 1;
                bool hit = v0 & (n2 >= 0) & (n2 < S2) & (((tv.x >> (n2 & 31)) & 1u) != 0);
                int rk = (int)tv.y + __popc(tv.x & ((1u << (n2 & 31)) - 1u));
                nbr[d0 * 3 + d2] = hit ? rk : -1;
            }
        }

        bool act[9];
#pragma unroll
        for (int t = 0; t < 9; ++t) act[t] = (__any(nbr[t] >= 0) != 0);

        // phase 2: 18 UNCONDITIONAL gathers; dead taps -> zero row n
        short8 A0[9], A1[9];
#pragma unroll
        for (int t = 0; t < 9; ++t) {
            int nbc = nbr[t] >= 0 ? nbr[t] : n;
            const short* fp = (const short*)featb + (size_t)nbc * CH;
            A0[t] = *(const short8*)(fp + half * 8);
            A1[t] = *(const short8*)(fp + 16 + half * 8);
        }

        // phase 3: MFMAs, skipping wave-dead taps
        f32x16 acc;
#pragma unroll
        for (int i = 0; i < 16; ++i) acc[i] = 0.f;
#pragma unroll
        for (int t = 0; t < 9; ++t) {
            if (act[t]) {
                acc = __builtin_amdgcn_mfma_f32_32x32x16_bf16(A0[t], B[t][0], acc, 0, 0, 0);
                acc = __builtin_amdgcn_mfma_f32_32x32x16_bf16(A1[t], B[t][1], acc, 0, 0, 0);
            }
        }

        // epilogue: LeakyReLU + bf16 coalesced store + stats
        // C/D layout: col = lane&31, row = (i&3) + 8*(i>>2) + 4*half
#pragma unroll
        for (int i = 0; i < 16; ++i) {
            float v = acc[i];
            v = v >= 0.f ? v : SLOPE * v;
            int row = (i & 3) + 8 * (i >> 2) + 4 * half;
            int prow = tile * 32 + row;
            if (prow < n) {
                xout[(size_t)prow * CH + col] = f2b(v);
                s += v; qq += v * v;
            }
        }
    }

    s  += __shfl_xor(s, 32);
    qq += __shfl_xor(qq, 32);

    __shared__ float lsum[4][32];
    __shared__ float lsq[4][32];
    if (lane < 32) { lsum[wv][col] = s; lsq[wv][col] = qq; }
    __syncthreads();
    if (tid < 32) {
        stats_part[(size_t)blockIdx.x * 64 + tid] =
            lsum[0][tid] + lsum[1][tid] + lsum[2][tid] + lsum[3][tid];
    } else if (tid < 64) {
        int cc = tid - 32;
        stats_part[(size_t)blockIdx.x * 64 + tid] =
            lsq[0][cc] + lsq[1][cc] + lsq[2][cc] + lsq[3][cc];
    }
}

// ---- deterministic partial reduce ---------------------------------------
__global__ __launch_bounds__(256) void reduce_stats_k(
    const float* __restrict__ part, float* __restrict__ stats, int nb)
{
    int c = blockIdx.x;            // 0..63
    float s = 0.f;
    for (int i = threadIdx.x; i < nb; i += 256)
        s += part[(size_t)i * 64 + c];
#pragma unroll
    for (int m = 32; m > 0; m >>= 1) s += __shfl_xor(s, m, 64);
    __shared__ float red[4];
    int wv = threadIdx.x >> 6;
    if ((threadIdx.x & 63) == 0) red[wv] = s;
    __syncthreads();
    if (threadIdx.x == 0) stats[c] = red[0] + red[1] + red[2] + red[3];
}

// ---- BN normalize: gather xb by rank, fully-coalesced fp32 out write ----
__global__ __launch_bounds__(256) void bn_gather_k(
    const unsigned short* __restrict__ xb,
    const int*   __restrict__ rankof,
    const float* __restrict__ stats,
    const float* __restrict__ gamma,
    const float* __restrict__ beta,
    float* __restrict__ out,
    int n)
{
    int total = n * 4;                        // (orig row, 8-ch slot) pairs
    int stride = gridDim.x * blockDim.x;      // multiple of 4
    int g = blockIdx.x * blockDim.x + threadIdx.x;
    int c8 = g & 3;

    float scale[8], shift[8];
    float rn = 1.0f / (float)n;
#pragma unroll
    for (int j = 0; j < 8; ++j) {
        int oc = c8 * 8 + j;
        float m  = stats[oc] * rn;
        float vv = stats[CH + oc] * rn - m * m;
        float iv = rsqrtf(vv + EPS) * gamma[oc];
        scale[j] = iv;
        shift[j] = beta[oc] - m * iv;
    }

    const short8* x8 = (const short8*)xb;
    for (; g < total; g += stride) {
        int i = g >> 2;                       // original row
        int rank = rankof[i];
        short8 v = x8[(size_t)rank * 4 + c8];
        float f[8];
#pragma unroll
        for (int j = 0; j < 8; ++j) {
            union { unsigned int u; float f; } w;
            w.u = ((unsigned int)(unsigned short)v[j]) << 16;
            f[j] = fmaf(w.f, scale[j], shift[j]);
        }
        float4* o = (float4*)(out + (size_t)i * CH + c8 * 8);  // coalesced
        o[0] = make_float4(f[0], f[1], f[2], f[3]);
        o[1] = make_float4(f[4], f[5], f[6], f[7]);
    }
}

extern "C" void kernel_launch(void* const* d_in, const int* in_sizes, int n_in,
                              void* d_out, int out_size, void* d_ws, size_t ws_size,
                              hipStream_t stream)
{
    const float* features = (const float*)d_in[0];
    const int4*  coords   = (const int4*)d_in[1];
    const float* weight   = (const float*)d_in[2];
    const float* gamma    = (const float*)d_in[3];
    const float* beta     = (const float*)d_in[4];
    float* out = (float*)d_out;

    int n = in_sizes[0] / CH;            // 400000
    int ntile = (n + 31) / 32;           // 12500
    int chunk = (ntile + 7) / 8;         // 1563
    int conv_blocks = 8 * ((chunk + 3) / 4);   // 3128

    // ws layout (256 B aligned sections)
    char* w = (char*)d_ws;
    unsigned int* mask = (unsigned int*)w;  w += (size_t)NCOL * 4;            // 1.38 MB
    uint2* tab = (uint2*)w;                 w += (size_t)NCOL * 8;            // 2.76 MB
    int* bsum = (int*)w;                    w += ((size_t)SCAN_BLKS * 4 + 255) & ~(size_t)255;
    uint2* pinfo = (uint2*)w;               w += (size_t)n * 8;               // 3.2 MB
    int* rankof = (int*)w;                  w += (size_t)n * 4;               // 1.6 MB
    unsigned short* featb = (unsigned short*)w; w += (size_t)(n + 4) * CH * 2; // 25.6 MB + zero row
    unsigned short* xout = (unsigned short*)w;  w += (size_t)n * CH * 2;      // 25.6 MB
    float* stats_part = (float*)w;          w += (size_t)conv_blocks * 64 * 4;
    short8* bfrag = (short8*)w;             w += 9 * 2 * 64 * sizeof(short8);
    float* stats = (float*)w;

    clear_k<<<(NCOL / 4 + 255) / 256, 256, 0, stream>>>(
        (uint4*)mask, (uint4*)(featb + (size_t)n * CH));
    scatter_or_k<<<(n + 255) / 256, 256, 0, stream>>>(coords, mask, n);
    scanA_k<<<SCAN_BLKS, 256, 0, stream>>>(mask, bsum, weight, bfrag);
    scanBC_k<<<SCAN_BLKS, 256, 0, stream>>>(mask, bsum, tab);
    rank_k<<<(n + 255) / 256, 256, 0, stream>>>(coords, tab, pinfo, rankof, n);
    pack_k<<<2048, 256, 0, stream>>>(features, pinfo, featb, n, ntile);

    conv_sorted_k<<<conv_blocks, 256, 0, stream>>>(
        featb, pinfo, tab, bfrag, xout, stats_part, n, ntile);

    reduce_stats_k<<<64, 256, 0, stream>>>(stats_part, stats, conv_blocks);

    bn_gather_k<<<2048, 256, 0, stream>>>(xout, rankof, stats, gamma, beta, out, n);
}